// Round 8
// baseline (716.361 us; speedup 1.0000x reference)
//
#include <hip/hip_runtime.h>

// Causal bag-of-words: out[b,t,c] = mean(x[b,0..t,c]).
// SINGLE-PASS, register-resident chunks, DEPTH-1 aggregate-only lookback.
//  - 2048 blocks (ticketed), one per (b,chunk); chunk = 32 rows = 64 KiB.
//  - Phase A: load own chunk into regs (16 float4/thread), publish per-column
//    chunk aggregate + release flag. Publication depends on NOTHING -> the
//    wait graph has depth 1 (R3's failure was a 512-deep chain of ~5us
//    cross-XCD hand-offs; this has exactly one hop).
//  - Phase W: threads 0..chunk-1 poll one predecessor flag each, in parallel.
//  - Phase S: sum predecessor aggregates from L2/L3 (parity-split halves).
//  - Phase C: prefix from registers, *rcp(t+1), nontemporal store.
// x is read from HBM exactly once. No cooperative launch, no grid.sync.
// Deadlock-free: tickets are acquired at block start; a block waits only on
// strictly smaller tickets, and publication precedes any wait.
//
// Shapes: B=8, T=8192, C=512 (row-major B,T,C). All float32.

constexpr int B    = 8;
constexpr int T    = 8192;
constexpr int C    = 512;
constexpr int C4   = C / 4;      // 128 float4 per row
constexpr int L    = 32;         // rows per chunk
constexpr int NCH  = T / L;      // 256 chunks per b
constexpr int NBLK = B * NCH;    // 2048 blocks
constexpr int RPT  = L / 2;      // 16 rows per thread

typedef float f32x4 __attribute__((ext_vector_type(4)));

__device__ __forceinline__ float4 f4add(float4 a, float4 b) {
    return make_float4(a.x + b.x, a.y + b.y, a.z + b.z, a.w + b.w);
}

__global__ __launch_bounds__(256) void cbow_init(uint* __restrict__ meta) {
    const int i = blockIdx.x * 256 + threadIdx.x;
    if (i < 16 + NBLK) meta[i] = 0u;
}

__global__ __launch_bounds__(256) void cbow_onepass(
        const float4* __restrict__ x, float4* __restrict__ out,
        uint* __restrict__ meta, float4* __restrict__ agg) {
    const int tx = threadIdx.x;
    const int c4 = tx & (C4 - 1);
    const int rg = tx >> 7;                  // half: rows 0-15 / 16-31

    __shared__ uint   s_ticket;
    __shared__ float4 part[2][C4];           // per-half 16-row sums
    __shared__ float4 pre[2][C4];            // parity-split prefix partials

    if (tx == 0) s_ticket = atomicAdd(meta, 1u);
    __syncthreads();
    const uint tk    = s_ticket;
    const int  b     = (int)(tk & (B - 1));
    const int  chunk = (int)(tk >> 3);
    const int  g     = b * NCH + chunk;
    uint* flags = meta + 16;

    // ---- Phase A: register-resident chunk load + aggregate publish -----
    const int r0 = chunk * L + rg * RPT;
    const float4* p = x + ((size_t)(b * T + r0)) * C4 + c4;
    float4 v[RPT];
#pragma unroll
    for (int k = 0; k < RPT; ++k) v[k] = p[(size_t)k * C4];

    float4 s = v[0];
#pragma unroll
    for (int k = 1; k < RPT; ++k) s = f4add(s, v[k]);
    part[rg][c4] = s;
    __syncthreads();

    if (rg == 0) agg[(size_t)g * C4 + c4] = f4add(part[0][c4], part[1][c4]);
    __threadfence();
    __syncthreads();
    if (tx == 0)
        __hip_atomic_store(&flags[g], 1u, __ATOMIC_RELEASE,
                           __HIP_MEMORY_SCOPE_AGENT);

    // ---- Phase W: parallel depth-1 wait (thread tx polls flag tx) ------
    if (tx < chunk) {
        while (__hip_atomic_load(&flags[b * NCH + tx], __ATOMIC_ACQUIRE,
                                 __HIP_MEMORY_SCOPE_AGENT) == 0u)
            __builtin_amdgcn_s_sleep(4);
    }
    __syncthreads();

    // ---- Phase S: sum predecessor aggregates (L2/L3-resident) ----------
    const float4* w = agg + (size_t)(b * NCH) * C4 + c4;
    float4 a0 = make_float4(0.f, 0.f, 0.f, 0.f);
    float4 a1 = a0, a2 = a0, a3 = a0;
    int j = rg;
    for (; j + 6 < chunk; j += 8) {
        a0 = f4add(a0, w[(size_t)(j + 0) * C4]);
        a1 = f4add(a1, w[(size_t)(j + 2) * C4]);
        a2 = f4add(a2, w[(size_t)(j + 4) * C4]);
        a3 = f4add(a3, w[(size_t)(j + 6) * C4]);
    }
    for (; j < chunk; j += 2) a0 = f4add(a0, w[(size_t)j * C4]);
    pre[rg][c4] = f4add(f4add(a0, a1), f4add(a2, a3));
    __syncthreads();

    // ---- Phase C: in-register scan, scale, NT store --------------------
    float4 run = f4add(pre[0][c4], pre[1][c4]);
    if (rg) run = f4add(run, part[0][c4]);

    float4* o = out + ((size_t)(b * T + r0)) * C4 + c4;
#pragma unroll
    for (int k = 0; k < RPT; ++k) {
        run = f4add(run, v[k]);
        const float inv = __builtin_amdgcn_rcpf((float)(r0 + k + 1));
        f32x4 val = {run.x * inv, run.y * inv, run.z * inv, run.w * inv};
        __builtin_nontemporal_store(val, (f32x4*)(o + (size_t)k * C4));
    }
}

extern "C" void kernel_launch(void* const* d_in, const int* in_sizes, int n_in,
                              void* d_out, int out_size, void* d_ws, size_t ws_size,
                              hipStream_t stream) {
    const float4* x   = (const float4*)d_in[0];
    float4*       out = (float4*)d_out;

    uint*   meta = (uint*)d_ws;
    float4* agg  = (float4*)((char*)d_ws + (64 << 10));  // 4 MiB used

    const int init_blocks = (16 + NBLK + 255) / 256;     // 9
    cbow_init<<<init_blocks, 256, 0, stream>>>(meta);
    cbow_onepass<<<NBLK, 256, 0, stream>>>(x, out, meta, agg);
}